// Round 13
// baseline (89.770 us; speedup 1.0000x reference)
//
#include <hip/hip_runtime.h>
#include <hip/hip_bf16.h>

#define N_NODES 50000
#define N_EDGES 600000
#define DIM 128
#define CAP 64            // slots per node; P(deg>=64) ~ 1.6e-28 for Poisson(12)
#define WLDS_STRIDE 136   // 128 + 8 ushort pad: 2-way alias on b128 reads (free)
#define GEMM_BLOCKS ((N_NODES + 63) / 64)          // 782
#define ZERO_BLOCKS ((N_NODES / 4 + 255) / 256)    // 49

typedef __attribute__((ext_vector_type(8))) short bf16x8;
typedef __attribute__((ext_vector_type(8))) unsigned short ushort8;
typedef __attribute__((ext_vector_type(4))) float floatx4;

// ---------------- fused gemm + cnt-zero dispatch ----------------
// blocks [0, GEMM_BLOCKS): Y = bf16(X @ W), 64 rows/block.
//   W staged from fp32 global with inline transpose+convert into LDS.
//   MFMA operands swapped (A=Wfrag, B=Xfrag) -> lane (m,q) holds
//   Y[wr+m][ct*16+q*4+r] -> 8x ushort4 coalesced stores. (round 9/12 proven)
// blocks [GEMM_BLOCKS, +ZERO_BLOCKS): zero the 50k counters.
__global__ __launch_bounds__(256) void k_gemm_zero(
        const float* __restrict__ X,
        const float* __restrict__ W,
        ushort* __restrict__ Y,
        int4* __restrict__ cnt4) {
    __shared__ ushort Wlds[DIM * WLDS_STRIDE];   // 34816 B
    int b = blockIdx.x;
    int t = threadIdx.x;

    if (b >= GEMM_BLOCKS) {
        int i = (b - GEMM_BLOCKS) * 256 + t;
        if (i < N_NODES / 4) cnt4[i] = make_int4(0, 0, 0, 0);
        return;
    }

    // stage: Wlds[n][k] = bf16(W[k][n]).
    // work item g: n = g&127 (lane-coalesced reads of W rows), k8 = g>>7.
#pragma unroll
    for (int i = 0; i < 8; ++i) {
        int g = t + 256 * i;
        int n = g & 127, k8 = g >> 7;
        ushort8 tmp;
#pragma unroll
        for (int j = 0; j < 8; ++j)
            tmp[j] = __bfloat16_as_ushort(
                __float2bfloat16(W[(size_t)(k8 * 8 + j) * DIM + n]));
        *(ushort8*)&Wlds[n * WLDS_STRIDE + k8 * 8] = tmp;
    }
    __syncthreads();

    int w = t >> 6, l = t & 63;
    int wr = b * 64 + w * 16;
    int m = l & 15, q = l >> 4;
    int rowA = wr + m;
    if (rowA >= N_NODES) rowA = N_NODES - 1;      // clamp loads; stores guarded
    const float* xp = X + (size_t)rowA * DIM + q * 8;

    floatx4 acc[8];
#pragma unroll
    for (int ct = 0; ct < 8; ++ct)
        acc[ct] = (floatx4){0.f, 0.f, 0.f, 0.f};

    const ushort* wl = &Wlds[m * WLDS_STRIDE + q * 8];
#pragma unroll
    for (int kk = 0; kk < 4; ++kk) {
        float4 x0 = *(const float4*)(xp + kk * 32);
        float4 x1 = *(const float4*)(xp + kk * 32 + 4);
        bf16x8 xf;
        xf[0] = (short)__bfloat16_as_ushort(__float2bfloat16(x0.x));
        xf[1] = (short)__bfloat16_as_ushort(__float2bfloat16(x0.y));
        xf[2] = (short)__bfloat16_as_ushort(__float2bfloat16(x0.z));
        xf[3] = (short)__bfloat16_as_ushort(__float2bfloat16(x0.w));
        xf[4] = (short)__bfloat16_as_ushort(__float2bfloat16(x1.x));
        xf[5] = (short)__bfloat16_as_ushort(__float2bfloat16(x1.y));
        xf[6] = (short)__bfloat16_as_ushort(__float2bfloat16(x1.z));
        xf[7] = (short)__bfloat16_as_ushort(__float2bfloat16(x1.w));
#pragma unroll
        for (int ct = 0; ct < 8; ++ct) {
            bf16x8 wf = *(const bf16x8*)(wl + (size_t)(ct * 16) * WLDS_STRIDE + kk * 32);
            acc[ct] = __builtin_amdgcn_mfma_f32_16x16x32_bf16(wf, xf, acc[ct], 0, 0, 0);
        }
    }

    int row = wr + m;
    if (row < N_NODES) {
        ushort* yp = Y + (size_t)row * DIM + q * 4;
#pragma unroll
        for (int ct = 0; ct < 8; ++ct) {
            ushort4 o;
            o.x = __bfloat16_as_ushort(__float2bfloat16(acc[ct][0]));
            o.y = __bfloat16_as_ushort(__float2bfloat16(acc[ct][1]));
            o.z = __bfloat16_as_ushort(__float2bfloat16(acc[ct][2]));
            o.w = __bfloat16_as_ushort(__float2bfloat16(acc[ct][3]));
            *(ushort4*)(yp + ct * 16) = o;
        }
    }
}

// ---------------- direct bucket fill (verbatim, proven) ----------------
__global__ __launch_bounds__(256) void k_fill_direct(
        const int* __restrict__ esrc,
        const int* __restrict__ edst,
        const float* __restrict__ ew,
        int* __restrict__ cnt,
        int2* __restrict__ slots) {
    int e = blockIdx.x * blockDim.x + threadIdx.x;
    if (e >= N_EDGES) return;
    int d = edst[e];
    int pos = atomicAdd(&cnt[d], 1);
    if (pos < CAP)
        slots[(size_t)d * CAP + pos] = make_int2(esrc[e], __float_as_int(ew[e]));
}

// ---------------- gather: 2 nodes per 16-lane group, interleaved ----------------
__device__ __forceinline__ float bf_lo(unsigned u) {
    return __uint_as_float(u << 16);
}
__device__ __forceinline__ float bf_hi(unsigned u) {
    return __uint_as_float(u & 0xFFFF0000u);
}

#define ACC8(A, W, Y4)                                        \
    A[0] += (W) * bf_lo((Y4).x); A[1] += (W) * bf_hi((Y4).x); \
    A[2] += (W) * bf_lo((Y4).y); A[3] += (W) * bf_hi((Y4).y); \
    A[4] += (W) * bf_lo((Y4).z); A[5] += (W) * bf_hi((Y4).z); \
    A[6] += (W) * bf_lo((Y4).w); A[7] += (W) * bf_hi((Y4).w);

__global__ __launch_bounds__(256) void k_gather2(
        const ushort* __restrict__ Y,
        const int* __restrict__ cnt,
        const int2* __restrict__ slots,
        const float* __restrict__ bias,
        float* __restrict__ out) {
    int grp = blockIdx.x * 16 + (threadIdx.x >> 4);
    int n0 = grp * 2, n1 = n0 + 1;
    int c = (threadIdx.x & 15) * 8;           // 8 dims per lane
    int dA = (n0 < N_NODES) ? cnt[n0] : 0; if (dA > CAP) dA = CAP;
    int dB = (n1 < N_NODES) ? cnt[n1] : 0; if (dB > CAP) dB = CAP;
    const int2* spA = slots + (size_t)n0 * CAP;
    const int2* spB = slots + (size_t)n1 * CAP;

    float a[8], bq[8];
#pragma unroll
    for (int k = 0; k < 8; ++k) { a[k] = 0.f; bq[k] = 0.f; }

    int dmax = dA > dB ? dA : dB;
    for (int j = 0; j < dmax; j += 4) {
        bool fA = (j + 4 <= dA), fB = (j + 4 <= dB);
        if (fA && fB) {
            // fast path: 8 independent Y loads in flight
            int4 sa0 = *(const int4*)(spA + j);
            int4 sa1 = *(const int4*)(spA + j + 2);
            int4 sb0 = *(const int4*)(spB + j);
            int4 sb1 = *(const int4*)(spB + j + 2);
            uint4 ya0 = *(const uint4*)(Y + (size_t)sa0.x * DIM + c);
            uint4 ya1 = *(const uint4*)(Y + (size_t)sa0.z * DIM + c);
            uint4 ya2 = *(const uint4*)(Y + (size_t)sa1.x * DIM + c);
            uint4 ya3 = *(const uint4*)(Y + (size_t)sa1.z * DIM + c);
            uint4 yb0 = *(const uint4*)(Y + (size_t)sb0.x * DIM + c);
            uint4 yb1 = *(const uint4*)(Y + (size_t)sb0.z * DIM + c);
            uint4 yb2 = *(const uint4*)(Y + (size_t)sb1.x * DIM + c);
            uint4 yb3 = *(const uint4*)(Y + (size_t)sb1.z * DIM + c);
            float wa0 = __int_as_float(sa0.y), wa1 = __int_as_float(sa0.w);
            float wa2 = __int_as_float(sa1.y), wa3 = __int_as_float(sa1.w);
            float wb0 = __int_as_float(sb0.y), wb1 = __int_as_float(sb0.w);
            float wb2 = __int_as_float(sb1.y), wb3 = __int_as_float(sb1.w);
            ACC8(a, wa0, ya0); ACC8(a, wa1, ya1);
            ACC8(a, wa2, ya2); ACC8(a, wa3, ya3);
            ACC8(bq, wb0, yb0); ACC8(bq, wb1, yb1);
            ACC8(bq, wb2, yb2); ACC8(bq, wb3, yb3);
        } else {
            if (fA) {
                int4 s0 = *(const int4*)(spA + j);
                int4 s1 = *(const int4*)(spA + j + 2);
                uint4 y0 = *(const uint4*)(Y + (size_t)s0.x * DIM + c);
                uint4 y1 = *(const uint4*)(Y + (size_t)s0.z * DIM + c);
                uint4 y2 = *(const uint4*)(Y + (size_t)s1.x * DIM + c);
                uint4 y3 = *(const uint4*)(Y + (size_t)s1.z * DIM + c);
                ACC8(a, __int_as_float(s0.y), y0);
                ACC8(a, __int_as_float(s0.w), y1);
                ACC8(a, __int_as_float(s1.y), y2);
                ACC8(a, __int_as_float(s1.w), y3);
            } else {
                for (int jj = j; jj < dA; ++jj) {
                    int2 m0 = spA[jj];
                    uint4 y0 = *(const uint4*)(Y + (size_t)m0.x * DIM + c);
                    ACC8(a, __int_as_float(m0.y), y0);
                }
            }
            if (fB) {
                int4 s0 = *(const int4*)(spB + j);
                int4 s1 = *(const int4*)(spB + j + 2);
                uint4 y0 = *(const uint4*)(Y + (size_t)s0.x * DIM + c);
                uint4 y1 = *(const uint4*)(Y + (size_t)s0.z * DIM + c);
                uint4 y2 = *(const uint4*)(Y + (size_t)s1.x * DIM + c);
                uint4 y3 = *(const uint4*)(Y + (size_t)s1.z * DIM + c);
                ACC8(bq, __int_as_float(s0.y), y0);
                ACC8(bq, __int_as_float(s0.w), y1);
                ACC8(bq, __int_as_float(s1.y), y2);
                ACC8(bq, __int_as_float(s1.w), y3);
            } else {
                for (int jj = j; jj < dB; ++jj) {
                    int2 m0 = spB[jj];
                    uint4 y0 = *(const uint4*)(Y + (size_t)m0.x * DIM + c);
                    ACC8(bq, __int_as_float(m0.y), y0);
                }
            }
        }
    }

    float4 bA = *(const float4*)(bias + c);
    float4 bB = *(const float4*)(bias + c + 4);
    if (n0 < N_NODES) {
        float* op = out + (size_t)n0 * DIM + c;
        *(float4*)(op + 0) = make_float4(a[0] + bA.x, a[1] + bA.y,
                                         a[2] + bA.z, a[3] + bA.w);
        *(float4*)(op + 4) = make_float4(a[4] + bB.x, a[5] + bB.y,
                                         a[6] + bB.z, a[7] + bB.w);
    }
    if (n1 < N_NODES) {
        float* op = out + (size_t)n1 * DIM + c;
        *(float4*)(op + 0) = make_float4(bq[0] + bA.x, bq[1] + bA.y,
                                         bq[2] + bA.z, bq[3] + bA.w);
        *(float4*)(op + 4) = make_float4(bq[4] + bB.x, bq[5] + bB.y,
                                         bq[6] + bB.z, bq[7] + bB.w);
    }
}

// ---------------- fallback path kernels (ws too small) ----------------
__global__ void zero_ws(float4* __restrict__ p, int n4) {
    int i = blockIdx.x * blockDim.x + threadIdx.x;
    if (i < n4) p[i] = make_float4(0.f, 0.f, 0.f, 0.f);
}

__global__ __launch_bounds__(256) void scatter_edges(
        const float* __restrict__ x,
        const float* __restrict__ ew,
        const int* __restrict__ esrc,
        const int* __restrict__ edst,
        float* __restrict__ agg) {
    long long t = (long long)blockIdx.x * blockDim.x + threadIdx.x;
    int e = (int)(t >> 5);
    if (e >= N_EDGES) return;
    int d4 = ((int)t & 31) * 4;
    int s = esrc[e];
    int d = edst[e];
    float w = ew[e];
    float4 xv = *(const float4*)(x + (size_t)s * DIM + d4);
    float* ap = agg + (size_t)d * DIM + d4;
    atomicAdd(ap + 0, w * xv.x);
    atomicAdd(ap + 1, w * xv.y);
    atomicAdd(ap + 2, w * xv.z);
    atomicAdd(ap + 3, w * xv.w);
}

__global__ __launch_bounds__(256) void gemm_f32_bias(
        const float* __restrict__ A,
        const float* __restrict__ W,
        const float* __restrict__ bias,
        float* __restrict__ out) {
    __shared__ float Ws[DIM][DIM];
    int tid = threadIdx.x;
    const float4* W4 = (const float4*)W;
    float4* Ws4 = (float4*)&Ws[0][0];
#pragma unroll
    for (int i = 0; i < 16; ++i) Ws4[tid + 256 * i] = W4[tid + 256 * i];
    __syncthreads();

    int row0 = blockIdx.x * 64 + (tid >> 5) * 8;
    int cg = (tid & 31) * 4;
    float4 b = *(const float4*)(bias + cg);
    float acc[8][4];
#pragma unroll
    for (int i = 0; i < 8; ++i) {
        acc[i][0] = b.x; acc[i][1] = b.y; acc[i][2] = b.z; acc[i][3] = b.w;
    }
    int rload[8];
#pragma unroll
    for (int i = 0; i < 8; ++i) {
        int r = row0 + i;
        rload[i] = (r < N_NODES) ? r : (N_NODES - 1);
    }
    for (int kt = 0; kt < 32; ++kt) {
        float4 xr[8];
#pragma unroll
        for (int i = 0; i < 8; ++i)
            xr[i] = *(const float4*)(A + (size_t)rload[i] * DIM + kt * 4);
        float4 wr[4];
#pragma unroll
        for (int j = 0; j < 4; ++j)
            wr[j] = *(const float4*)&Ws[kt * 4 + j][cg];
#pragma unroll
        for (int i = 0; i < 8; ++i) {
            acc[i][0] += xr[i].x * wr[0].x + xr[i].y * wr[1].x + xr[i].z * wr[2].x + xr[i].w * wr[3].x;
            acc[i][1] += xr[i].x * wr[0].y + xr[i].y * wr[1].y + xr[i].z * wr[2].y + xr[i].w * wr[3].y;
            acc[i][2] += xr[i].x * wr[0].z + xr[i].y * wr[1].z + xr[i].z * wr[2].z + xr[i].w * wr[3].z;
            acc[i][3] += xr[i].x * wr[0].w + xr[i].y * wr[1].w + xr[i].z * wr[2].w + xr[i].w * wr[3].w;
        }
    }
#pragma unroll
    for (int i = 0; i < 8; ++i) {
        int row = row0 + i;
        if (row >= N_NODES) break;
        *(float4*)(out + (size_t)row * DIM + cg) =
            make_float4(acc[i][0], acc[i][1], acc[i][2], acc[i][3]);
    }
}

extern "C" void kernel_launch(void* const* d_in, const int* in_sizes, int n_in,
                              void* d_out, int out_size, void* d_ws, size_t ws_size,
                              hipStream_t stream) {
    const float* batch_x     = (const float*)d_in[0];
    const float* edge_weight = (const float*)d_in[1];
    const float* weight      = (const float*)d_in[2];
    const float* bias        = (const float*)d_in[3];
    const int*   edge_src    = (const int*)d_in[4];
    const int*   edge_dst    = (const int*)d_in[5];
    float* out = (float*)d_out;

    auto align256 = [](size_t x) { return (x + 255) & ~(size_t)255; };
    char* ws = (char*)d_ws;

    size_t oY    = 0;                                                        // 12.8 MB
    size_t oCnt  = align256(oY + (size_t)N_NODES * DIM * sizeof(ushort));    // 200 KB
    size_t oSlot = align256(oCnt + (size_t)N_NODES * sizeof(int));           // 25.6 MB
    size_t needed = oSlot + (size_t)N_NODES * CAP * sizeof(int2);

    if (ws_size >= needed) {
        ushort* Y    = (ushort*)(ws + oY);
        int*    cnt  = (int*)(ws + oCnt);
        int2*   slot = (int2*)(ws + oSlot);

        // 1) Y = bf16(X @ W) via MFMA (inline W transpose); side blocks zero cnt
        k_gemm_zero<<<GEMM_BLOCKS + ZERO_BLOCKS, 256, 0, stream>>>(
            batch_x, weight, Y, (int4*)cnt);

        // 2) direct bucket fill
        k_fill_direct<<<(N_EDGES + 255) / 256, 256, 0, stream>>>(
            edge_src, edge_dst, edge_weight, cnt, slot);

        // 3) gather + bias (2 nodes per 16-lane group)
        k_gather2<<<((N_NODES + 1) / 2 + 15) / 16, 256, 0, stream>>>(
            Y, cnt, slot, bias, out);
    } else {
        // fallback: atomic path (needs 25.6 MB)
        float* agg = (float*)d_ws;
        int n4 = N_NODES * DIM / 4;
        zero_ws<<<(n4 + 255) / 256, 256, 0, stream>>>((float4*)agg, n4);
        long long threads = (long long)N_EDGES * 32;
        scatter_edges<<<(int)((threads + 255) / 256), 256, 0, stream>>>(
            batch_x, edge_weight, edge_src, edge_dst, agg);
        gemm_f32_bias<<<(N_NODES + 63) / 64, 256, 0, stream>>>(
            agg, weight, bias, out);
    }
}

// Round 14
// 81.432 us; speedup vs baseline: 1.1024x; 1.1024x over previous
//
#include <hip/hip_runtime.h>
#include <hip/hip_bf16.h>

#define N_NODES 50000
#define N_EDGES 600000
#define DIM 128
#define CAP 64            // slots per node; P(deg>=64) ~ 1.6e-28 for Poisson(12)
#define WLDS_STRIDE 136   // 128 + 8 ushort pad: 2-way alias on b128 reads (free)

typedef __attribute__((ext_vector_type(8))) short bf16x8;
typedef __attribute__((ext_vector_type(4))) float floatx4;

// ---------------- prep: Wt[n][k] = bf16(W[k][n]); also zero cnt ----------------
// (verbatim round 8/12, proven)
__global__ __launch_bounds__(256) void k_prep(const float* __restrict__ W,
                                              ushort* __restrict__ Wt,
                                              int4* __restrict__ cnt4) {
    int b = blockIdx.x;
    if (b < 16) {
        int idx = (b * 256 + threadIdx.x) * 4;
        float4 v = *(const float4*)(W + idx);
        int k = idx >> 7, n = idx & 127;
        Wt[(size_t)(n + 0) * DIM + k] = __bfloat16_as_ushort(__float2bfloat16(v.x));
        Wt[(size_t)(n + 1) * DIM + k] = __bfloat16_as_ushort(__float2bfloat16(v.y));
        Wt[(size_t)(n + 2) * DIM + k] = __bfloat16_as_ushort(__float2bfloat16(v.z));
        Wt[(size_t)(n + 3) * DIM + k] = __bfloat16_as_ushort(__float2bfloat16(v.w));
    } else {
        int i = (b - 16) * 256 + threadIdx.x;
        if (i < N_NODES / 4) cnt4[i] = make_int4(0, 0, 0, 0);
    }
}

// ---------------- direct bucket fill (verbatim, proven) ----------------
__global__ __launch_bounds__(256) void k_fill_direct(
        const int* __restrict__ esrc,
        const int* __restrict__ edst,
        const float* __restrict__ ew,
        int* __restrict__ cnt,
        int2* __restrict__ slots) {
    int e = blockIdx.x * blockDim.x + threadIdx.x;
    if (e >= N_EDGES) return;
    int d = edst[e];
    int pos = atomicAdd(&cnt[d], 1);
    if (pos < CAP)
        slots[(size_t)d * CAP + pos] = make_int2(esrc[e], __float_as_int(ew[e]));
}

// ---------------- MFMA GEMM (verbatim round 12, proven): Y = bf16(X @ W) -----
__global__ __launch_bounds__(256) void gemm_mfma(
        const float* __restrict__ X,
        const ushort* __restrict__ Wt,
        ushort* __restrict__ Y) {
    __shared__ ushort Wlds[DIM * WLDS_STRIDE];   // 34816 B
    int t = threadIdx.x;

#pragma unroll
    for (int i = 0; i < 8; ++i) {
        int g = t + 256 * i;
        int n = g >> 4, c = g & 15;
        *(uint4*)&Wlds[n * WLDS_STRIDE + c * 8] = ((const uint4*)Wt)[g];
    }
    __syncthreads();

    int w = t >> 6, l = t & 63;
    int wr = blockIdx.x * 64 + w * 16;
    int m = l & 15, q = l >> 4;
    int rowA = wr + m;
    if (rowA >= N_NODES) rowA = N_NODES - 1;      // clamp loads; stores guarded
    const float* xp = X + (size_t)rowA * DIM + q * 8;

    floatx4 acc[8];
#pragma unroll
    for (int ct = 0; ct < 8; ++ct)
        acc[ct] = (floatx4){0.f, 0.f, 0.f, 0.f};

    const ushort* wl = &Wlds[m * WLDS_STRIDE + q * 8];
#pragma unroll
    for (int kk = 0; kk < 4; ++kk) {
        float4 x0 = *(const float4*)(xp + kk * 32);
        float4 x1 = *(const float4*)(xp + kk * 32 + 4);
        bf16x8 xf;
        xf[0] = (short)__bfloat16_as_ushort(__float2bfloat16(x0.x));
        xf[1] = (short)__bfloat16_as_ushort(__float2bfloat16(x0.y));
        xf[2] = (short)__bfloat16_as_ushort(__float2bfloat16(x0.z));
        xf[3] = (short)__bfloat16_as_ushort(__float2bfloat16(x0.w));
        xf[4] = (short)__bfloat16_as_ushort(__float2bfloat16(x1.x));
        xf[5] = (short)__bfloat16_as_ushort(__float2bfloat16(x1.y));
        xf[6] = (short)__bfloat16_as_ushort(__float2bfloat16(x1.z));
        xf[7] = (short)__bfloat16_as_ushort(__float2bfloat16(x1.w));
#pragma unroll
        for (int ct = 0; ct < 8; ++ct) {
            bf16x8 wf = *(const bf16x8*)(wl + (size_t)(ct * 16) * WLDS_STRIDE + kk * 32);
            acc[ct] = __builtin_amdgcn_mfma_f32_16x16x32_bf16(wf, xf, acc[ct], 0, 0, 0);
        }
    }

    int row = wr + m;
    if (row < N_NODES) {
        ushort* yp = Y + (size_t)row * DIM + q * 4;
#pragma unroll
        for (int ct = 0; ct < 8; ++ct) {
            ushort4 o;
            o.x = __bfloat16_as_ushort(__float2bfloat16(acc[ct][0]));
            o.y = __bfloat16_as_ushort(__float2bfloat16(acc[ct][1]));
            o.z = __bfloat16_as_ushort(__float2bfloat16(acc[ct][2]));
            o.w = __bfloat16_as_ushort(__float2bfloat16(acc[ct][3]));
            *(ushort4*)(yp + ct * 16) = o;
        }
    }
}

// ---------------- gather: 16 lanes/node, predicated 16-edge prefetch ----------
// Per chunk: 8 broadcast int4 slot loads (CAP-padded table, always readable),
// predicated idx/w selects, then ALL 16 Y uint4 loads issued together ->
// one slot-latency + one Y-latency per chunk (deg<=16 for ~90% of nodes).
__device__ __forceinline__ float bf_lo(unsigned u) {
    return __uint_as_float(u << 16);
}
__device__ __forceinline__ float bf_hi(unsigned u) {
    return __uint_as_float(u & 0xFFFF0000u);
}

#define ACC8(A, W, Y4)                                        \
    A[0] += (W) * bf_lo((Y4).x); A[1] += (W) * bf_hi((Y4).x); \
    A[2] += (W) * bf_lo((Y4).y); A[3] += (W) * bf_hi((Y4).y); \
    A[4] += (W) * bf_lo((Y4).z); A[5] += (W) * bf_hi((Y4).z); \
    A[6] += (W) * bf_lo((Y4).w); A[7] += (W) * bf_hi((Y4).w);

__global__ __launch_bounds__(256) void k_gather_pf(
        const ushort* __restrict__ Y,
        const int* __restrict__ cnt,
        const int2* __restrict__ slots,
        const float* __restrict__ bias,
        float* __restrict__ out) {
    int node = blockIdx.x * 16 + (threadIdx.x >> 4);
    if (node >= N_NODES) return;
    int c = (threadIdx.x & 15) * 8;           // 8 dims per lane
    int deg = cnt[node];
    if (deg > CAP) deg = CAP;
    const int4* sp4 = (const int4*)(slots + (size_t)node * CAP);

    float a0[8], a1[8];
#pragma unroll
    for (int k = 0; k < 8; ++k) { a0[k] = 0.f; a1[k] = 0.f; }

    for (int base = 0; base < deg; base += 16) {
        int4 s[8];
#pragma unroll
        for (int i = 0; i < 8; ++i) s[i] = sp4[(base >> 1) + i];

        int   idx[16];
        float wgt[16];
#pragma unroll
        for (int i = 0; i < 8; ++i) {
            int j0 = base + 2 * i, j1 = j0 + 1;
            idx[2 * i]     = (j0 < deg) ? s[i].x : 0;
            wgt[2 * i]     = (j0 < deg) ? __int_as_float(s[i].y) : 0.f;
            idx[2 * i + 1] = (j1 < deg) ? s[i].z : 0;
            wgt[2 * i + 1] = (j1 < deg) ? __int_as_float(s[i].w) : 0.f;
        }

        uint4 y[16];
#pragma unroll
        for (int i = 0; i < 16; ++i)
            y[i] = *(const uint4*)(Y + (size_t)idx[i] * DIM + c);

#pragma unroll
        for (int i = 0; i < 16; i += 2) {
            ACC8(a0, wgt[i], y[i]);
            ACC8(a1, wgt[i + 1], y[i + 1]);
        }
    }

    float4 bA = *(const float4*)(bias + c);
    float4 bB = *(const float4*)(bias + c + 4);
    float* op = out + (size_t)node * DIM + c;
    *(float4*)(op + 0) = make_float4(a0[0] + a1[0] + bA.x, a0[1] + a1[1] + bA.y,
                                     a0[2] + a1[2] + bA.z, a0[3] + a1[3] + bA.w);
    *(float4*)(op + 4) = make_float4(a0[4] + a1[4] + bB.x, a0[5] + a1[5] + bB.y,
                                     a0[6] + a1[6] + bB.z, a0[7] + a1[7] + bB.w);
}

// ---------------- fallback path kernels (ws too small) ----------------
__global__ void zero_ws(float4* __restrict__ p, int n4) {
    int i = blockIdx.x * blockDim.x + threadIdx.x;
    if (i < n4) p[i] = make_float4(0.f, 0.f, 0.f, 0.f);
}

__global__ __launch_bounds__(256) void scatter_edges(
        const float* __restrict__ x,
        const float* __restrict__ ew,
        const int* __restrict__ esrc,
        const int* __restrict__ edst,
        float* __restrict__ agg) {
    long long t = (long long)blockIdx.x * blockDim.x + threadIdx.x;
    int e = (int)(t >> 5);
    if (e >= N_EDGES) return;
    int d4 = ((int)t & 31) * 4;
    int s = esrc[e];
    int d = edst[e];
    float w = ew[e];
    float4 xv = *(const float4*)(x + (size_t)s * DIM + d4);
    float* ap = agg + (size_t)d * DIM + d4;
    atomicAdd(ap + 0, w * xv.x);
    atomicAdd(ap + 1, w * xv.y);
    atomicAdd(ap + 2, w * xv.z);
    atomicAdd(ap + 3, w * xv.w);
}

__global__ __launch_bounds__(256) void gemm_f32_bias(
        const float* __restrict__ A,
        const float* __restrict__ W,
        const float* __restrict__ bias,
        float* __restrict__ out) {
    __shared__ float Ws[DIM][DIM];
    int tid = threadIdx.x;
    const float4* W4 = (const float4*)W;
    float4* Ws4 = (float4*)&Ws[0][0];
#pragma unroll
    for (int i = 0; i < 16; ++i) Ws4[tid + 256 * i] = W4[tid + 256 * i];
    __syncthreads();

    int row0 = blockIdx.x * 64 + (tid >> 5) * 8;
    int cg = (tid & 31) * 4;
    float4 b = *(const float4*)(bias + cg);
    float acc[8][4];
#pragma unroll
    for (int i = 0; i < 8; ++i) {
        acc[i][0] = b.x; acc[i][1] = b.y; acc[i][2] = b.z; acc[i][3] = b.w;
    }
    int rload[8];
#pragma unroll
    for (int i = 0; i < 8; ++i) {
        int r = row0 + i;
        rload[i] = (r < N_NODES) ? r : (N_NODES - 1);
    }
    for (int kt = 0; kt < 32; ++kt) {
        float4 xr[8];
#pragma unroll
        for (int i = 0; i < 8; ++i)
            xr[i] = *(const float4*)(A + (size_t)rload[i] * DIM + kt * 4);
        float4 wr[4];
#pragma unroll
        for (int j = 0; j < 4; ++j)
            wr[j] = *(const float4*)&Ws[kt * 4 + j][cg];
#pragma unroll
        for (int i = 0; i < 8; ++i) {
            acc[i][0] += xr[i].x * wr[0].x + xr[i].y * wr[1].x + xr[i].z * wr[2].x + xr[i].w * wr[3].x;
            acc[i][1] += xr[i].x * wr[0].y + xr[i].y * wr[1].y + xr[i].z * wr[2].y + xr[i].w * wr[3].y;
            acc[i][2] += xr[i].x * wr[0].z + xr[i].y * wr[1].z + xr[i].z * wr[2].z + xr[i].w * wr[3].z;
            acc[i][3] += xr[i].x * wr[0].w + xr[i].y * wr[1].w + xr[i].z * wr[2].w + xr[i].w * wr[3].w;
        }
    }
#pragma unroll
    for (int i = 0; i < 8; ++i) {
        int row = row0 + i;
        if (row >= N_NODES) break;
        *(float4*)(out + (size_t)row * DIM + cg) =
            make_float4(acc[i][0], acc[i][1], acc[i][2], acc[i][3]);
    }
}

extern "C" void kernel_launch(void* const* d_in, const int* in_sizes, int n_in,
                              void* d_out, int out_size, void* d_ws, size_t ws_size,
                              hipStream_t stream) {
    const float* batch_x     = (const float*)d_in[0];
    const float* edge_weight = (const float*)d_in[1];
    const float* weight      = (const float*)d_in[2];
    const float* bias        = (const float*)d_in[3];
    const int*   edge_src    = (const int*)d_in[4];
    const int*   edge_dst    = (const int*)d_in[5];
    float* out = (float*)d_out;

    auto align256 = [](size_t x) { return (x + 255) & ~(size_t)255; };
    char* ws = (char*)d_ws;

    size_t oY    = 0;                                                        // 12.8 MB
    size_t oCnt  = align256(oY + (size_t)N_NODES * DIM * sizeof(ushort));    // 200 KB
    size_t oSlot = align256(oCnt + (size_t)N_NODES * sizeof(int));           // 25.6 MB
    size_t oWt   = align256(oSlot + (size_t)N_NODES * CAP * sizeof(int2));   // 32 KB
    size_t needed = oWt + (size_t)DIM * DIM * sizeof(ushort);

    if (ws_size >= needed) {
        ushort* Y    = (ushort*)(ws + oY);
        int*    cnt  = (int*)(ws + oCnt);
        int2*   slot = (int2*)(ws + oSlot);
        ushort* Wt   = (ushort*)(ws + oWt);

        // 1) prep W (transpose+bf16) and zero counters
        k_prep<<<16 + (N_NODES / 4 + 255) / 256, 256, 0, stream>>>(
            weight, Wt, (int4*)cnt);

        // 2) direct bucket fill
        k_fill_direct<<<(N_EDGES + 255) / 256, 256, 0, stream>>>(
            edge_src, edge_dst, edge_weight, cnt, slot);

        // 3) Y = bf16(X @ W) via MFMA
        gemm_mfma<<<(N_NODES + 63) / 64, 256, 0, stream>>>(batch_x, Wt, Y);

        // 4) gather + bias (predicated 16-edge prefetch)
        k_gather_pf<<<(N_NODES + 15) / 16, 256, 0, stream>>>(
            Y, cnt, slot, bias, out);
    } else {
        // fallback: atomic path (needs 25.6 MB)
        float* agg = (float*)d_ws;
        int n4 = N_NODES * DIM / 4;
        zero_ws<<<(n4 + 255) / 256, 256, 0, stream>>>((float4*)agg, n4);
        long long threads = (long long)N_EDGES * 32;
        scatter_edges<<<(int)((threads + 255) / 256), 256, 0, stream>>>(
            batch_x, edge_weight, edge_src, edge_dst, agg);
        gemm_f32_bias<<<(N_NODES + 63) / 64, 256, 0, stream>>>(
            agg, weight, bias, out);
    }
}